// Round 1
// baseline (131.212 us; speedup 1.0000x reference)
//
#include <hip/hip_runtime.h>

typedef __attribute__((ext_vector_type(8))) short bf16x8;
typedef __attribute__((ext_vector_type(4))) float f32x4;

#define MFMA_BF16 __builtin_amdgcn_mfma_f32_16x16x32_bf16

__device__ __forceinline__ unsigned short f2bf(float f) {
  union { float f; unsigned u; } v; v.f = f;
  unsigned r = v.u + 0x7FFFu + ((v.u >> 16) & 1u);
  return (unsigned short)(r >> 16);
}
__device__ __forceinline__ float sigm(float x) {
  return __builtin_amdgcn_rcpf(1.f + __expf(-x));
}
__device__ __forceinline__ float tanh_f(float x) {
  // tanh(x) = 1 - 2/(1+e^{2x}); saturates correctly at +/-inf
  return 1.f - 2.f * __builtin_amdgcn_rcpf(1.f + __expf(2.f * x));
}

// ---------------------------------------------------------------------------
// K1: x = relu(layernorm(obs @ W0 + b0)) -> bf16 [131072, 64]
// block = 256 thr (4 waves), wave w handles 16 rows; 2048 blocks.
// W0 staged to LDS transposed [n=64][k=512] bf16, byte ^= (n&7)<<4 swizzle.
// ---------------------------------------------------------------------------
__global__ __launch_bounds__(256, 2) void k_dense_ln(
    const float* __restrict__ obs, const float* __restrict__ W0,
    const float* __restrict__ b0, const float* __restrict__ gam,
    const float* __restrict__ bet, unsigned short* __restrict__ xout) {
  __shared__ unsigned short wt[64 * 512];  // 64KB
  const int tid = threadIdx.x;
  for (int idx = tid; idx < 64 * 512; idx += 256) {
    int k = idx >> 6, n = idx & 63;
    unsigned off = ((unsigned)(n * 1024 + k * 2)) ^ ((unsigned)(n & 7) << 4);
    *(unsigned short*)((char*)wt + off) = f2bf(W0[idx]);
  }
  __syncthreads();

  const int w = tid >> 6, l = tid & 63;
  const int g = l >> 4, c = l & 15;
  const long rb = (long)blockIdx.x * 64 + w * 16;

  float b0v[4], gv[4], bv[4];
#pragma unroll
  for (int nt = 0; nt < 4; ++nt) {
    int col = nt * 16 + c;
    b0v[nt] = b0[col]; gv[nt] = gam[col]; bv[nt] = bet[col];
  }

  f32x4 acc[4];
#pragma unroll
  for (int nt = 0; nt < 4; ++nt) acc[nt] = (f32x4){0.f, 0.f, 0.f, 0.f};

  const float* arow = obs + (rb + c) * 512 + g * 8;  // A row m = lane&15
#pragma unroll 4
  for (int kf = 0; kf < 16; ++kf) {
    float4 a0 = *(const float4*)(arow + kf * 32);
    float4 a1 = *(const float4*)(arow + kf * 32 + 4);
    bf16x8 af;
    af[0] = (short)f2bf(a0.x); af[1] = (short)f2bf(a0.y);
    af[2] = (short)f2bf(a0.z); af[3] = (short)f2bf(a0.w);
    af[4] = (short)f2bf(a1.x); af[5] = (short)f2bf(a1.y);
    af[6] = (short)f2bf(a1.z); af[7] = (short)f2bf(a1.w);
#pragma unroll
    for (int nt = 0; nt < 4; ++nt) {
      unsigned off = ((unsigned)((nt * 16 + c) * 1024 + kf * 64 + g * 16)) ^
                     ((unsigned)(c & 7) << 4);
      bf16x8 bfr = *(const bf16x8*)((const char*)wt + off);
      acc[nt] = MFMA_BF16(af, bfr, acc[nt], 0, 0, 0);
    }
  }

  // D layout: row = 4*(l>>4)+r (within wave's 16-row tile), col = nt*16 + (l&15)
  float vv[4][4], s1[4], s2[4];
#pragma unroll
  for (int r = 0; r < 4; ++r) { s1[r] = 0.f; s2[r] = 0.f; }
#pragma unroll
  for (int nt = 0; nt < 4; ++nt)
#pragma unroll
    for (int r = 0; r < 4; ++r) {
      float val = acc[nt][r] + b0v[nt];
      vv[nt][r] = val; s1[r] += val; s2[r] += val * val;
    }
  // row owned by the 16 lanes sharing l>>4 ; xor masks 1,2,4,8 stay in-group
#pragma unroll
  for (int r = 0; r < 4; ++r) {
#pragma unroll
    for (int m = 1; m <= 8; m <<= 1) {
      s1[r] += __shfl_xor(s1[r], m);
      s2[r] += __shfl_xor(s2[r], m);
    }
  }
#pragma unroll
  for (int r = 0; r < 4; ++r) {
    float mu = s1[r] * 0.015625f;
    float var = s2[r] * 0.015625f - mu * mu;
    float inv = rsqrtf(var + 1e-12f);
    long row = rb + 4 * g + r;
#pragma unroll
    for (int nt = 0; nt < 4; ++nt) {
      float xn = (vv[nt][r] - mu) * inv * gv[nt] + bv[nt];
      xn = fmaxf(xn, 0.f);
      xout[row * 64 + nt * 16 + c] = f2bf(xn);
    }
  }
}

// ---------------------------------------------------------------------------
// K2: bidirectional LSTM + fused output projection.
// 512 blocks: blk<256 -> fw, else bw. Each block: 16 sequences, all 32 steps.
// Wave w owns gate n-tiles {w, w+4, w+8, w+12} -> all 4 gates of (s,u) in regs.
// W (bf16 frags) entirely in registers; x-tile (64KB) and h (2KB) in LDS.
// ---------------------------------------------------------------------------
__global__ __launch_bounds__(256, 2) void k_lstm(
    const unsigned short* __restrict__ x, const float* __restrict__ Wfw,
    const float* __restrict__ bfw, const float* __restrict__ Wbw,
    const float* __restrict__ bbw, const float* __restrict__ Wc,
    const float* __restrict__ bc, float* __restrict__ out) {
  __shared__ unsigned short xl[16 * 32 * 64];  // 64KB, swizzled
  __shared__ unsigned short hl[16 * 64];       // 2KB, swizzled
  const int tid = threadIdx.x, w = tid >> 6, l = tid & 63;
  const int g = l >> 4, c = l & 15;
  const int dir = blockIdx.x >> 8;
  const int sq = (blockIdx.x & 255) * 16;
  const float* W = dir ? Wbw : Wfw;
  const float* bias = dir ? bbw : bfw;

  // B fragments in registers: col = gate*64 + w*16 + c, k = kf*32 + g*8 + j
  bf16x8 Bf[4][4];
#pragma unroll
  for (int gate = 0; gate < 4; ++gate) {
    const int col = gate * 64 + w * 16 + c;
#pragma unroll
    for (int kf = 0; kf < 4; ++kf)
#pragma unroll
      for (int j = 0; j < 8; ++j)
        Bf[gate][kf][j] = (short)f2bf(W[(kf * 32 + g * 8 + j) * 256 + col]);
  }
  float bz[4];
#pragma unroll
  for (int gate = 0; gate < 4; ++gate) bz[gate] = bias[gate * 64 + w * 16 + c];

  // projection B-frags (wave 0 only uses them); cols >= 8 padded w/ zeros
  bf16x8 Pc[2];
#pragma unroll
  for (int kf = 0; kf < 2; ++kf)
#pragma unroll
    for (int j = 0; j < 8; ++j) Pc[kf][j] = 0;
  float bcv = 0.f;
  if (w == 0 && c < 8) {
#pragma unroll
    for (int kf = 0; kf < 2; ++kf)
#pragma unroll
      for (int j = 0; j < 8; ++j)
        Pc[kf][j] = (short)f2bf(Wc[(kf * 32 + g * 8 + j) * 8 + c]);
    bcv = bc[c];
  }

  // stage the block's x tile: 512 contiguous rows of 64 bf16 (64KB)
  const unsigned short* xg = x + (long)sq * 2048;
  for (int q = tid; q < 4096; q += 256) {
    bf16x8 v = *(const bf16x8*)(xg + q * 8);
    unsigned dst = ((unsigned)(q * 16)) ^ ((((unsigned)q >> 8) & 7u) << 4);
    *(bf16x8*)((char*)xl + dst) = v;
  }
  for (int i = tid; i < 512; i += 256) ((unsigned*)hl)[i] = 0u;
  float cs[4] = {0.f, 0.f, 0.f, 0.f};
  __syncthreads();

  const unsigned hoff0 = ((unsigned)(c * 128 + g * 16)) ^ ((unsigned)(c & 7) << 4);

  for (int t = 0; t < 32; ++t) {
    const int te = dir ? 31 - t : t;
    // A-frags: x part (rows m = c, local row = c*32+te), h part from hl
    unsigned xoff = ((unsigned)((c * 32 + te) * 128 + g * 16)) ^
                    ((unsigned)(c & 7) << 4);
    bf16x8 Ax0 = *(const bf16x8*)((const char*)xl + xoff);
    bf16x8 Ax1 = *(const bf16x8*)((const char*)xl + (xoff ^ 64u));
    bf16x8 Ah0 = *(const bf16x8*)((const char*)hl + hoff0);
    bf16x8 Ah1 = *(const bf16x8*)((const char*)hl + (hoff0 ^ 64u));

    f32x4 acc[4];
#pragma unroll
    for (int gate = 0; gate < 4; ++gate)
      acc[gate] = (f32x4){bz[gate], bz[gate], bz[gate], bz[gate]};
#pragma unroll
    for (int gate = 0; gate < 4; ++gate) {
      acc[gate] = MFMA_BF16(Ax0, Bf[gate][0], acc[gate], 0, 0, 0);
      acc[gate] = MFMA_BF16(Ax1, Bf[gate][1], acc[gate], 0, 0, 0);
      acc[gate] = MFMA_BF16(Ah0, Bf[gate][2], acc[gate], 0, 0, 0);
      acc[gate] = MFMA_BF16(Ah1, Bf[gate][3], acc[gate], 0, 0, 0);
    }

    // gates: acc[0]=i, acc[1]=j, acc[2]=f, acc[3]=o ; (s = 4g+r, u = w*16+c)
    unsigned short hb[4];
#pragma unroll
    for (int r = 0; r < 4; ++r) {
      float si = sigm(acc[0][r]);
      float tj = tanh_f(acc[1][r]);
      float sf = sigm(acc[2][r] + 1.f);  // forget_bias = 1.0
      float so = sigm(acc[3][r]);
      cs[r] = cs[r] * sf + si * tj;
      hb[r] = f2bf(tanh_f(cs[r]) * so);
    }
    __syncthreads();  // everyone done reading h(t-1)
#pragma unroll
    for (int r = 0; r < 4; ++r) {
      int s = 4 * g + r;
      unsigned off = ((unsigned)(s * 128 + (w * 16 + c) * 2)) ^
                     ((unsigned)(s & 7) << 4);
      *(unsigned short*)((char*)hl + off) = hb[r];
    }
    __syncthreads();  // h(t) visible

    // fused projection: out[dir*B + sq + s][te][a] = tanh(h @ Wc + bc)
    if (w == 0) {
      bf16x8 Ph0 = *(const bf16x8*)((const char*)hl + hoff0);
      bf16x8 Ph1 = *(const bf16x8*)((const char*)hl + (hoff0 ^ 64u));
      f32x4 pa = (f32x4){0.f, 0.f, 0.f, 0.f};
      pa = MFMA_BF16(Ph0, Pc[0], pa, 0, 0, 0);
      pa = MFMA_BF16(Ph1, Pc[1], pa, 0, 0, 0);
      if (c < 8) {
#pragma unroll
        for (int r = 0; r < 4; ++r) {
          long orow = (long)dir * 4096 + sq + 4 * g + r;
          out[(orow * 32 + te) * 8 + c] = tanh_f(pa[r] + bcv);
        }
      }
    }
  }
}

extern "C" void kernel_launch(void* const* d_in, const int* in_sizes, int n_in,
                              void* d_out, int out_size, void* d_ws, size_t ws_size,
                              hipStream_t stream) {
  const float* obs = (const float*)d_in[0];
  const float* W0  = (const float*)d_in[1];
  const float* b0  = (const float*)d_in[2];
  const float* gam = (const float*)d_in[3];
  const float* bet = (const float*)d_in[4];
  const float* Wfw = (const float*)d_in[5];
  const float* bfw = (const float*)d_in[6];
  const float* Wbw = (const float*)d_in[7];
  const float* bbw = (const float*)d_in[8];
  const float* Wc  = (const float*)d_in[9];
  const float* bc  = (const float*)d_in[10];
  float* out = (float*)d_out;
  unsigned short* xbf = (unsigned short*)d_ws;  // 131072*64 bf16 = 16.8 MB

  k_dense_ln<<<2048, 256, 0, stream>>>(obs, W0, b0, gam, bet, xbf);
  k_lstm<<<512, 256, 0, stream>>>(xbf, Wfw, bfw, Wbw, bbw, Wc, bc, out);
}